// Round 17
// baseline (2498.711 us; speedup 1.0000x reference)
//
#include <hip/hip_runtime.h>

// PopulationODE: sequential RK4 scan, T=4096 (T%4==0), state=4, HID=32.
// Round-17: FOUR steps in flight (16 waves, 4 waves/SIMD).
//   grp g = step 4j+g, stage st. Stage inputs extrapolated (g+1) steps:
//   (g+2)*g1 - (g+1)*g0 from steps 4j-1, 4j-2. y/zb for grp>=1 from exact
//   y(4j) + extrapolated combines (k+2)*C3-(k+1)*C2. One packed exchange
//   + ONE barrier per FOUR steps. Eval latencies hide across 4 waves/SIMD.
// Numerics lineage: r8 zero-order -> 0.0; r14 1-step extrap -> 0.0078;
// r15/16 2-step -> 0.0078 (1 output bf16 ulp). Worst extrap here ~10x r14
// base, contraction gain ~1e-3/step. Stage math identical to r7-r16.

__device__ __forceinline__ float fexp2(float x) { return __builtin_amdgcn_exp2f(x); }
__device__ __forceinline__ float frcp(float x) { return __builtin_amdgcn_rcpf(x); }
#define C_TANH 2.8853900817779268f
#define C_NSIG (-1.4426950408889634f)

template<int CTRL>
__device__ __forceinline__ float dppmov(float x) {
  return __int_as_float(__builtin_amdgcn_update_dpp(
      0, __float_as_int(x), CTRL, 0xF, 0xF, true));
}
#define RORc(K) (0x120 | (K))

__device__ __forceinline__ void p16swap(float& a, float& b) {
  asm("s_nop 1\n\tv_permlane16_swap_b32 %0, %1" : "+v"(a), "+v"(b));
}
__device__ __forceinline__ void p32swap(float& a, float& b) {
  asm("s_nop 1\n\tv_permlane32_swap_b32 %0, %1" : "+v"(a), "+v"(b));
}

// 16 MACs, 8 streams, guaranteed DPP-fused (r16, bit-identical to r15).
#define MV8(W, BZ, X, SOUT) do {                                            \
    float b0_ = fmaf((X), W[0], (BZ));                                      \
    float b1_, b2_, b3_, b4_, b5_, b6_, b7_;                                \
    asm("s_nop 1\n\t"                                                       \
        "v_mul_f32_dpp %1, %8, %9 row_ror:1 row_mask:0xf bank_mask:0xf\n\t" \
        "v_mul_f32_dpp %2, %8, %10 row_ror:2 row_mask:0xf bank_mask:0xf\n\t"\
        "v_mul_f32_dpp %3, %8, %11 row_ror:3 row_mask:0xf bank_mask:0xf\n\t"\
        "v_mul_f32_dpp %4, %8, %12 row_ror:4 row_mask:0xf bank_mask:0xf\n\t"\
        "v_mul_f32_dpp %5, %8, %13 row_ror:5 row_mask:0xf bank_mask:0xf\n\t"\
        "v_mul_f32_dpp %6, %8, %14 row_ror:6 row_mask:0xf bank_mask:0xf\n\t"\
        "v_mul_f32_dpp %7, %8, %15 row_ror:7 row_mask:0xf bank_mask:0xf\n\t"\
        "v_fmac_f32_dpp %0, %8, %16 row_ror:8 row_mask:0xf bank_mask:0xf\n\t"\
        "v_fmac_f32_dpp %1, %8, %17 row_ror:9 row_mask:0xf bank_mask:0xf\n\t"\
        "v_fmac_f32_dpp %2, %8, %18 row_ror:10 row_mask:0xf bank_mask:0xf\n\t"\
        "v_fmac_f32_dpp %3, %8, %19 row_ror:11 row_mask:0xf bank_mask:0xf\n\t"\
        "v_fmac_f32_dpp %4, %8, %20 row_ror:12 row_mask:0xf bank_mask:0xf\n\t"\
        "v_fmac_f32_dpp %5, %8, %21 row_ror:13 row_mask:0xf bank_mask:0xf\n\t"\
        "v_fmac_f32_dpp %6, %8, %22 row_ror:14 row_mask:0xf bank_mask:0xf\n\t"\
        "v_fmac_f32_dpp %7, %8, %23 row_ror:15 row_mask:0xf bank_mask:0xf"  \
        : "+v"(b0_), "=&v"(b1_), "=&v"(b2_), "=&v"(b3_),                    \
          "=&v"(b4_), "=&v"(b5_), "=&v"(b6_), "=&v"(b7_)                    \
        : "v"(X), "v"(W[1]), "v"(W[2]), "v"(W[3]), "v"(W[4]),               \
          "v"(W[5]), "v"(W[6]), "v"(W[7]), "v"(W[8]), "v"(W[9]),            \
          "v"(W[10]), "v"(W[11]), "v"(W[12]), "v"(W[13]), "v"(W[14]),       \
          "v"(W[15]));                                                      \
    SOUT = ((b0_ + b1_) + (b2_ + b3_)) + ((b4_ + b5_) + (b6_ + b7_));       \
  } while (0)

__global__ __launch_bounds__(1024, 1) __attribute__((amdgpu_waves_per_eu(4, 4)))
void ode_kernel(const float* __restrict__ s_grid,
                const float* __restrict__ y0in,
                const float* __restrict__ Win,
                const float* __restrict__ bin_,
                const float* __restrict__ W1a, const float* __restrict__ b1a,
                const float* __restrict__ W1b, const float* __restrict__ b1b,
                const float* __restrict__ W2a, const float* __restrict__ b2a,
                const float* __restrict__ W2b, const float* __restrict__ b2b,
                const float* __restrict__ Wout, const float* __restrict__ bout,
                const float* __restrict__ Aarr,
                float* __restrict__ out, int T) {
  const int tid = threadIdx.x;
  const int wv = tid >> 6;        // 0..15
  const int grp = wv >> 2;        // step 4j+grp
  const int st = wv & 3;          // RK stage owned
  const int lane = tid & 63;
  const int i = lane & 15;
  const int m = lane >> 4;
  const int mlo = m & 1;
  const int mhi = m >> 1;

  // ---- LDS ----
  __shared__ float s_lds[4096];
  __shared__ __align__(16) float2 PK[2][2][16]; // [buf][half][slot]=(Ka,Kb)
  __shared__ __align__(16) float GK[2][16];     // [buf][slot]=gk
  for (int idx = tid; idx < T && idx < 4096; idx += 1024)
    s_lds[idx] = s_grid[idx];
  __syncthreads();

  // ---- direction probes ----
  int delta;
  {
    float pr = (float)i;
    float pr1 = dppmov<RORc(1)>(pr);
    delta = (((int)pr1) - i) & 15;
  }
  bool p32_c_low;
  {
    float v = (float)(lane >> 5);
    float c = v, d = v;
    p32swap(c, d);
    p32_c_low = (c == 0.0f);
  }

  // ---- weight prep (identical to r7-r16) ----
  const int rA = 16 * mhi + i, hA = mlo;
  const int rB = 16 * mlo + i, hB = mhi;
  const int r_in = 16 * mlo + i;
  const int e1 = r_in;

  float w1a[16], w2a[16], m21[16];
#pragma unroll 1
  for (int k = 0; k < 16; ++k) {
    int cA = hA * 16 + ((i + delta * k) & 15);
    int cB = hB * 16 + ((i + delta * k) & 15);
    w1a[k] = W1a[rA * 32 + cA] * (-2.0f * C_TANH);
    w2a[k] = W2a[rA * 32 + cA] * (-2.0f * C_TANH);
    float acc = 0.0f;
    for (int q = 0; q < 32; ++q)
      acc = fmaf(W2a[rB * 32 + q], W1b[q * 32 + cB], acc);
    m21[k] = acc * (-2.0f * C_TANH);
  }
  float bz1a;
  {
    float rs = 0.0f;
    for (int c = 0; c < 32; ++c) rs += W1a[rA * 32 + c];
    bz1a = hA ? 0.0f : C_TANH * (b1a[rA] + rs);
  }
  float c2sel;
  {
    float rs2a = 0.0f, m21rs = 0.0f, wb = 0.0f;
    for (int q = 0; q < 32; ++q) {
      float w2q = W2a[rB * 32 + q];
      rs2a += w2q;
      float rs1bq = 0.0f;
      for (int c = 0; c < 32; ++c) rs1bq += W1b[q * 32 + c];
      m21rs = fmaf(w2q, rs1bq, m21rs);
      wb = fmaf(w2q, b1b[q], wb);
    }
    c2sel = hB ? 0.0f : C_TANH * (rs2a + m21rs + wb + b2a[rB]);
  }
  const bool seedsel = (mlo == mhi);

  float winy0 = Win[r_in * 5 + 0] * C_TANH;
  float winy1 = Win[r_in * 5 + 1] * C_TANH;
  float winy2 = Win[r_in * 5 + 2] * C_TANH;
  float winy3 = Win[r_in * 5 + 3] * C_TANH;
  float wins  = Win[r_in * 5 + 4] * C_TANH;
  float binr  = bin_[r_in] * C_TANH;
  float gsel_a = mhi ? winy2 : winy0;
  float gsel_b = mhi ? winy3 : winy1;

  const int ra_ = 2 * mhi, rb_ = 2 * mhi + 1;
  float woXa = Wout[ra_ * 32 + e1] * (-2.0f * C_NSIG);
  float woXb = Wout[rb_ * 32 + e1] * (-2.0f * C_NSIG);
  float wo1a, wo1b, wo2a, wo2b, boa, bob;
  {
    float w1s_a = 0.0f, w1s_b = 0.0f, w2s_a = 0.0f, w2s_b = 0.0f;
    float rsX_a = 0.0f, rsX_b = 0.0f, rs1_a = 0.0f, rs1_b = 0.0f;
    float rs2_a = 0.0f, rs2_b = 0.0f, bt_a = 0.0f, bt_b = 0.0f;
    for (int q = 0; q < 32; ++q) {
      float waq = Wout[ra_ * 32 + q], wbq = Wout[rb_ * 32 + q];
      w1s_a = fmaf(waq, W1b[q * 32 + e1], w1s_a);
      w1s_b = fmaf(wbq, W1b[q * 32 + e1], w1s_b);
      w2s_a = fmaf(waq, W2b[q * 32 + e1], w2s_a);
      w2s_b = fmaf(wbq, W2b[q * 32 + e1], w2s_b);
      rsX_a += waq; rsX_b += wbq;
      float rs1bq = 0.0f, rs2bq = 0.0f;
      for (int c = 0; c < 32; ++c) {
        rs1bq += W1b[q * 32 + c];
        rs2bq += W2b[q * 32 + c];
      }
      rs1_a = fmaf(waq, rs1bq, rs1_a); rs1_b = fmaf(wbq, rs1bq, rs1_b);
      rs2_a = fmaf(waq, rs2bq, rs2_a); rs2_b = fmaf(wbq, rs2bq, rs2_b);
      float bs = b1b[q] + b2b[q];
      bt_a = fmaf(waq, bs, bt_a); bt_b = fmaf(wbq, bs, bt_b);
    }
    wo1a = w1s_a * (-2.0f * C_NSIG); wo1b = w1s_b * (-2.0f * C_NSIG);
    wo2a = w2s_a * (-2.0f * C_NSIG); wo2b = w2s_b * (-2.0f * C_NSIG);
    boa = (bout[ra_] + bt_a + rsX_a + rs1_a + rs2_a) * (C_NSIG / 32.0f);
    bob = (bout[rb_] + bt_b + rsX_b + rs1_b + rs2_b) * (C_NSIG / 32.0f);
  }
  float Aa = mhi ? Aarr[2] : Aarr[0];
  float Ab = mhi ? Aarr[3] : Aarr[1];

  auto relayout = [&](float v) -> float {
    float c = v, d = v;
    p32swap(c, d);
    float lo = p32_c_low ? c : d;
    float hi = p32_c_low ? d : c;
    return mlo ? hi : lo;
  };

  float pfa, pfb, wpa, wpb, na, nb, gkv;

  auto setpref = [&](float yA, float yB) {
    float sa = frcp(1.0f + fexp2(yA * C_NSIG));
    float sb = frcp(1.0f + fexp2(yB * C_NSIG));
    pfa = 0.01f * sa * (Aa - sa);
    pfb = 0.01f * sb * (Ab - sb);
    wpa = gsel_a * pfa;
    wpb = gsel_b * pfb;
  };

  auto STAGE = [&](float zin) {
    float g0v = frcp(fexp2(zin) + 1.0f);                   // ABAB
    float u1; MV8(w1a, bz1a, g0v, u1);
    { float b = u1; p16swap(u1, b); u1 += b; }             // AABB
    float q2; MV8(w2a, 0.0f, g0v, q2);
    { float b = q2; p16swap(q2, b); q2 += b; }             // AABB
    float g1 = frcp(fexp2(u1) + 1.0f);
    float g1r = relayout(g1);
    float seed = (seedsel ? q2 : 0.0f) + c2sel;
    float u2; MV8(m21, seed, g1, u2);
    { float b = u2; p32swap(u2, b); u2 += b; }             // ABAB
    float g2 = frcp(fexp2(u2) + 1.0f);
    float ph0 = fmaf(wo1a, g1r, fmaf(woXa, g0v, boa));
    float ph1 = fmaf(wo1b, g1r, fmaf(woXb, g0v, bob));
    float p0 = fmaf(wo2a, g2, ph0);
    float p1 = fmaf(wo2b, g2, ph1);
    p0 += dppmov<RORc(8)>(p0); p1 += dppmov<RORc(8)>(p1);
    p0 += dppmov<RORc(4)>(p0); p1 += dppmov<RORc(4)>(p1);
    p0 += dppmov<RORc(2)>(p0); p1 += dppmov<RORc(2)>(p1);
    p0 += dppmov<RORc(1)>(p0); p1 += dppmov<RORc(1)>(p1);
    { float q = p0; p16swap(p0, q); p0 += q; }
    { float q = p1; p16swap(p1, q); p1 += q; }
    na = frcp(1.0f + fexp2(p0));
    nb = frcp(1.0f + fexp2(p1));
    float gp = fmaf(wpb, nb, wpa * na);
    float gq = gp;
    p32swap(gp, gq);
    gkv = gp + gq;
  };

  auto wrslot = [&](int qq, float Ka, float Kb) {
    if ((lane & 31) == 0)
      PK[qq][mhi][wv] = make_float2(Ka, Kb);
    if (lane == 0)
      GK[qq][wv] = gkv;
  };

  // ---- state (every wave tracks identically; lags the pipeline) ----
  float y00 = y0in[0], y01 = y0in[1], y02 = y0in[2], y03 = y0in[3];
  float ya = mhi ? y02 : y00;
  float yb = mhi ? y03 : y01;

  if (wv == 0 && (lane & 0x1E) == 0)
    out[(lane >> 4) + (lane & 1)] = (lane & 1) ? yb : ya;

  float zb = fmaf(winy0, y00, fmaf(winy1, y01, fmaf(winy2, y02,
             fmaf(winy3, y03, fmaf(wins, s_lds[0], binr)))));

  // ---- prologue: zero-input sweeps seed buf[1] (pseudo steps -4..-1) ----
  {
    int gi = grp < T ? grp : T - 1;
    float sg = s_lds[gi];
    setpref(ya, yb);
    STAGE(fmaf(wins, sg - s_lds[0], zb));
    wrslot(1, pfa * na, pfb * nb);
  }
  __syncthreads();

  float h6p0 = 0.0f, h6p1 = 0.0f, h6p2 = 0.0f, h6p3 = 0.0f, hsumP = 0.0f;
  const int NJ = T >> 2;   // iterations; steps 4j..4j+3 (tail evals dummy)

  for (int j = 0; j < NJ; ++j) {
    const int w = j & 1, r = w ^ 1;
    int i0 = 4 * j;
    float s0v = s_lds[i0];
    float s1v = s_lds[i0 + 1 < T ? i0 + 1 : T - 1];
    float s2v = s_lds[i0 + 2 < T ? i0 + 2 : T - 1];
    float s3v = s_lds[i0 + 3 < T ? i0 + 3 : T - 1];
    float s4v = s_lds[i0 + 4 < T ? i0 + 4 : T - 1];
    float h0 = s1v - s0v, h1 = s2v - s1v, h2 = s3v - s2v, h3 = s4v - s3v;
    float h6_0 = h0 * (1.0f / 6.0f), h6_1 = h1 * (1.0f / 6.0f);
    float h6_2 = h2 * (1.0f / 6.0f), h6_3 = h3 * (1.0f / 6.0f);

    // ---- batched reads from buf r (steps 4j-4 .. 4j-1) ----
    float4 pv0 = *(const float4*)&PK[r][mhi][0];
    float4 pv1 = *(const float4*)&PK[r][mhi][2];
    float4 pv2 = *(const float4*)&PK[r][mhi][4];
    float4 pv3 = *(const float4*)&PK[r][mhi][6];
    float4 pv4 = *(const float4*)&PK[r][mhi][8];
    float4 pv5 = *(const float4*)&PK[r][mhi][10];
    float4 pv6 = *(const float4*)&PK[r][mhi][12];
    float4 pv7 = *(const float4*)&PK[r][mhi][14];
    float4 gv0 = *(const float4*)&GK[r][0];
    float4 gv1 = *(const float4*)&GK[r][4];
    float4 gv2 = *(const float4*)&GK[r][8];
    float4 gv3 = *(const float4*)&GK[r][12];
    // RK combines {1,2,2,1} per step k=0..3
    float aC0 = fmaf(2.0f, pv0.z, pv0.x); aC0 = fmaf(2.0f, pv1.x, aC0); aC0 += pv1.z;
    float bC0 = fmaf(2.0f, pv0.w, pv0.y); bC0 = fmaf(2.0f, pv1.y, bC0); bC0 += pv1.w;
    float gC0 = fmaf(2.0f, gv0.y, gv0.x); gC0 = fmaf(2.0f, gv0.z, gC0); gC0 += gv0.w;
    float aC1 = fmaf(2.0f, pv2.z, pv2.x); aC1 = fmaf(2.0f, pv3.x, aC1); aC1 += pv3.z;
    float bC1 = fmaf(2.0f, pv2.w, pv2.y); bC1 = fmaf(2.0f, pv3.y, bC1); bC1 += pv3.w;
    float gC1 = fmaf(2.0f, gv1.y, gv1.x); gC1 = fmaf(2.0f, gv1.z, gC1); gC1 += gv1.w;
    float aC2 = fmaf(2.0f, pv4.z, pv4.x); aC2 = fmaf(2.0f, pv5.x, aC2); aC2 += pv5.z;
    float bC2 = fmaf(2.0f, pv4.w, pv4.y); bC2 = fmaf(2.0f, pv5.y, bC2); bC2 += pv5.w;
    float gC2 = fmaf(2.0f, gv2.y, gv2.x); gC2 = fmaf(2.0f, gv2.z, gC2); gC2 += gv2.w;
    float aC3 = fmaf(2.0f, pv6.z, pv6.x); aC3 = fmaf(2.0f, pv7.x, aC3); aC3 += pv7.z;
    float bC3 = fmaf(2.0f, pv6.w, pv6.y); bC3 = fmaf(2.0f, pv7.y, bC3); bC3 += pv7.w;
    float gC3 = fmaf(2.0f, gv3.y, gv3.x); gC3 = fmaf(2.0f, gv3.z, gC3); gC3 += gv3.w;
    // own-stage input history: steps 4j-2 (slots 8+sl), 4j-1 (slots 12+sl)
    const int sl = st ? st - 1 : 0;
    float2 pk0 = PK[r][mhi][8 + sl];
    float2 pk1 = PK[r][mhi][12 + sl];
    float g0i = GK[r][8 + sl], g1i = GK[r][12 + sl];

    // ---- finalize exact y(4j-3)..y(4j) (j>=1) ----
    if (j) {
      float y1a = fmaf(h6p0, aC0, ya), y1b = fmaf(h6p0, bC0, yb);
      float y2a = fmaf(h6p1, aC1, y1a), y2b = fmaf(h6p1, bC1, y1b);
      float y3a = fmaf(h6p2, aC2, y2a), y3b = fmaf(h6p2, bC2, y2b);
      ya = fmaf(h6p3, aC3, y3a);
      yb = fmaf(h6p3, bC3, y3b);
      float zacc = fmaf(h6p0, gC0, fmaf(wins, hsumP, zb));
      zacc = fmaf(h6p1, gC1, zacc);
      zacc = fmaf(h6p2, gC2, zacc);
      zb = fmaf(h6p3, gC3, zacc);
      if (wv == 0 && (lane & 0x1E) == 0) {
        const size_t t0 = (size_t)(4 * j - 3);
        const int c = (lane >> 4) + (lane & 1);
        out[t0 * 4 + c] = (lane & 1) ? y1b : y1a;
        out[(t0 + 1) * 4 + c] = (lane & 1) ? y2b : y2a;
        out[(t0 + 2) * 4 + c] = (lane & 1) ? y3b : y3a;
        out[(t0 + 3) * 4 + c] = (lane & 1) ? yb : ya;
      }
    }

    // ---- extrapolated same-step stage inputs: (g+2)*g1 - (g+1)*g0 ----
    float fg = (float)(grp + 1);
    float gin  = fmaf(fg, g1i - g0i, g1i);
    float kain = fmaf(fg, pk1.x - pk0.x, pk1.x);
    float kbin = fmaf(fg, pk1.y - pk0.y, pk1.y);

    // ---- y/zb guesses for grp>=1 via extrapolated combines ----
    float yA = ya, yB = yb;
    float sg = (grp == 0) ? s0v : (grp == 1) ? s1v : (grp == 2) ? s2v : s3v;
    float zB = fmaf(wins, sg - s0v, zb);
    float dA = aC3 - aC2, dB = bC3 - bC2, dG = gC3 - gC2;
#pragma unroll
    for (int k = 0; k < 3; ++k) {
      if (k < grp) {
        float fk = (float)(k + 1);
        float ea = fmaf(fk, dA, aC3);
        float eb = fmaf(fk, dB, bC3);
        float eg = fmaf(fk, dG, gC3);
        float h6k = (k == 0) ? h6_0 : (k == 1) ? h6_1 : h6_2;
        yA = fmaf(h6k, ea, yA);
        yB = fmaf(h6k, eb, yB);
        zB = fmaf(h6k, eg, zB);
      }
    }
    float hg = (grp == 0) ? h0 : (grp == 1) ? h1 : (grp == 2) ? h2 : h3;
    float cw = (st == 0) ? 0.0f : (st == 3) ? hg : 0.5f * hg;

    setpref(fmaf(cw, kain, yA), fmaf(cw, kbin, yB));
    STAGE(fmaf(cw, gin, zB));
    wrslot(w, pfa * na, pfb * nb);

    h6p0 = h6_0; h6p1 = h6_1; h6p2 = h6_2; h6p3 = h6_3;
    hsumP = (h0 + h1) + (h2 + h3);
    __syncthreads();
  }

  // ---- epilogue: finalize y(T-3)..y(T-1) from last-written buf ----
  if (T > 1) {
    const int rr = (NJ - 1) & 1;
    float4 pv0 = *(const float4*)&PK[rr][mhi][0];
    float4 pv1 = *(const float4*)&PK[rr][mhi][2];
    float4 pv2 = *(const float4*)&PK[rr][mhi][4];
    float4 pv3 = *(const float4*)&PK[rr][mhi][6];
    float4 pv4 = *(const float4*)&PK[rr][mhi][8];
    float4 pv5 = *(const float4*)&PK[rr][mhi][10];
    float aC0 = fmaf(2.0f, pv0.z, pv0.x); aC0 = fmaf(2.0f, pv1.x, aC0); aC0 += pv1.z;
    float bC0 = fmaf(2.0f, pv0.w, pv0.y); bC0 = fmaf(2.0f, pv1.y, bC0); bC0 += pv1.w;
    float aC1 = fmaf(2.0f, pv2.z, pv2.x); aC1 = fmaf(2.0f, pv3.x, aC1); aC1 += pv3.z;
    float bC1 = fmaf(2.0f, pv2.w, pv2.y); bC1 = fmaf(2.0f, pv3.y, bC1); bC1 += pv3.w;
    float aC2 = fmaf(2.0f, pv4.z, pv4.x); aC2 = fmaf(2.0f, pv5.x, aC2); aC2 += pv5.z;
    float bC2 = fmaf(2.0f, pv4.w, pv4.y); bC2 = fmaf(2.0f, pv5.y, bC2); bC2 += pv5.w;
    float y1a = fmaf(h6p0, aC0, ya), y1b = fmaf(h6p0, bC0, yb);
    float y2a = fmaf(h6p1, aC1, y1a), y2b = fmaf(h6p1, bC1, y1b);
    float y3a = fmaf(h6p2, aC2, y2a), y3b = fmaf(h6p2, bC2, y2b);
    if (wv == 0 && (lane & 0x1E) == 0) {
      const size_t t0 = (size_t)(T - 3);
      const int c = (lane >> 4) + (lane & 1);
      out[t0 * 4 + c] = (lane & 1) ? y1b : y1a;
      out[(t0 + 1) * 4 + c] = (lane & 1) ? y2b : y2a;
      out[(t0 + 2) * 4 + c] = (lane & 1) ? y3b : y3a;
    }
  }
}

extern "C" void kernel_launch(void* const* d_in, const int* in_sizes, int n_in,
                              void* d_out, int out_size, void* d_ws, size_t ws_size,
                              hipStream_t stream) {
  const float* s_grid = (const float*)d_in[0];
  const float* y0 = (const float*)d_in[1];
  const float* Win = (const float*)d_in[2];
  const float* bin_ = (const float*)d_in[3];
  const float* W1a = (const float*)d_in[4];
  const float* b1a = (const float*)d_in[5];
  const float* W1b = (const float*)d_in[6];
  const float* b1b = (const float*)d_in[7];
  const float* W2a = (const float*)d_in[8];
  const float* b2a = (const float*)d_in[9];
  const float* W2b = (const float*)d_in[10];
  const float* b2b = (const float*)d_in[11];
  const float* Wout = (const float*)d_in[12];
  const float* bout = (const float*)d_in[13];
  const float* A = (const float*)d_in[14];
  int T = in_sizes[0];

  ode_kernel<<<1, 1024, 0, stream>>>(s_grid, y0, Win, bin_, W1a, b1a, W1b, b1b,
                                     W2a, b2a, W2b, b2b, Wout, bout, A,
                                     (float*)d_out, T);
}

// Round 18
// 2498.182 us; speedup vs baseline: 1.0002x; 1.0002x over previous
//
#include <hip/hip_runtime.h>

// PopulationODE: sequential RK4 scan, T=4096 (T%4==0), state=4, HID=32.
// Round-18: r17 (4 steps in flight, 16 waves) with ONE change:
//   amdgpu_waves_per_eu(1, 4)  [was (4,4)]
// r17's regression fingerprint: VGPR_Count=64 -- at 1024 threads the
// allocator targeted 8-waves/EU (64-VGPR budget), demoting the 48
// register-resident weights (AGPR shuffles back in every eval).
// min=1 restores the relaxed budget that yielded 84 VGPRs at 256/512
// threads (r11-r16); 84 <= 128 still allows 4 waves/SIMD residency.
// All math identical to r17 (passed, absmax 0.0078125).

__device__ __forceinline__ float fexp2(float x) { return __builtin_amdgcn_exp2f(x); }
__device__ __forceinline__ float frcp(float x) { return __builtin_amdgcn_rcpf(x); }
#define C_TANH 2.8853900817779268f
#define C_NSIG (-1.4426950408889634f)

template<int CTRL>
__device__ __forceinline__ float dppmov(float x) {
  return __int_as_float(__builtin_amdgcn_update_dpp(
      0, __float_as_int(x), CTRL, 0xF, 0xF, true));
}
#define RORc(K) (0x120 | (K))

__device__ __forceinline__ void p16swap(float& a, float& b) {
  asm("s_nop 1\n\tv_permlane16_swap_b32 %0, %1" : "+v"(a), "+v"(b));
}
__device__ __forceinline__ void p32swap(float& a, float& b) {
  asm("s_nop 1\n\tv_permlane32_swap_b32 %0, %1" : "+v"(a), "+v"(b));
}

// 16 MACs, 8 streams, guaranteed DPP-fused (r16, bit-identical to r15).
#define MV8(W, BZ, X, SOUT) do {                                            \
    float b0_ = fmaf((X), W[0], (BZ));                                      \
    float b1_, b2_, b3_, b4_, b5_, b6_, b7_;                                \
    asm("s_nop 1\n\t"                                                       \
        "v_mul_f32_dpp %1, %8, %9 row_ror:1 row_mask:0xf bank_mask:0xf\n\t" \
        "v_mul_f32_dpp %2, %8, %10 row_ror:2 row_mask:0xf bank_mask:0xf\n\t"\
        "v_mul_f32_dpp %3, %8, %11 row_ror:3 row_mask:0xf bank_mask:0xf\n\t"\
        "v_mul_f32_dpp %4, %8, %12 row_ror:4 row_mask:0xf bank_mask:0xf\n\t"\
        "v_mul_f32_dpp %5, %8, %13 row_ror:5 row_mask:0xf bank_mask:0xf\n\t"\
        "v_mul_f32_dpp %6, %8, %14 row_ror:6 row_mask:0xf bank_mask:0xf\n\t"\
        "v_mul_f32_dpp %7, %8, %15 row_ror:7 row_mask:0xf bank_mask:0xf\n\t"\
        "v_fmac_f32_dpp %0, %8, %16 row_ror:8 row_mask:0xf bank_mask:0xf\n\t"\
        "v_fmac_f32_dpp %1, %8, %17 row_ror:9 row_mask:0xf bank_mask:0xf\n\t"\
        "v_fmac_f32_dpp %2, %8, %18 row_ror:10 row_mask:0xf bank_mask:0xf\n\t"\
        "v_fmac_f32_dpp %3, %8, %19 row_ror:11 row_mask:0xf bank_mask:0xf\n\t"\
        "v_fmac_f32_dpp %4, %8, %20 row_ror:12 row_mask:0xf bank_mask:0xf\n\t"\
        "v_fmac_f32_dpp %5, %8, %21 row_ror:13 row_mask:0xf bank_mask:0xf\n\t"\
        "v_fmac_f32_dpp %6, %8, %22 row_ror:14 row_mask:0xf bank_mask:0xf\n\t"\
        "v_fmac_f32_dpp %7, %8, %23 row_ror:15 row_mask:0xf bank_mask:0xf"  \
        : "+v"(b0_), "=&v"(b1_), "=&v"(b2_), "=&v"(b3_),                    \
          "=&v"(b4_), "=&v"(b5_), "=&v"(b6_), "=&v"(b7_)                    \
        : "v"(X), "v"(W[1]), "v"(W[2]), "v"(W[3]), "v"(W[4]),               \
          "v"(W[5]), "v"(W[6]), "v"(W[7]), "v"(W[8]), "v"(W[9]),            \
          "v"(W[10]), "v"(W[11]), "v"(W[12]), "v"(W[13]), "v"(W[14]),       \
          "v"(W[15]));                                                      \
    SOUT = ((b0_ + b1_) + (b2_ + b3_)) + ((b4_ + b5_) + (b6_ + b7_));       \
  } while (0)

__global__ __launch_bounds__(1024, 1) __attribute__((amdgpu_waves_per_eu(1, 4)))
void ode_kernel(const float* __restrict__ s_grid,
                const float* __restrict__ y0in,
                const float* __restrict__ Win,
                const float* __restrict__ bin_,
                const float* __restrict__ W1a, const float* __restrict__ b1a,
                const float* __restrict__ W1b, const float* __restrict__ b1b,
                const float* __restrict__ W2a, const float* __restrict__ b2a,
                const float* __restrict__ W2b, const float* __restrict__ b2b,
                const float* __restrict__ Wout, const float* __restrict__ bout,
                const float* __restrict__ Aarr,
                float* __restrict__ out, int T) {
  const int tid = threadIdx.x;
  const int wv = tid >> 6;        // 0..15
  const int grp = wv >> 2;        // step 4j+grp
  const int st = wv & 3;          // RK stage owned
  const int lane = tid & 63;
  const int i = lane & 15;
  const int m = lane >> 4;
  const int mlo = m & 1;
  const int mhi = m >> 1;

  // ---- LDS ----
  __shared__ float s_lds[4096];
  __shared__ __align__(16) float2 PK[2][2][16]; // [buf][half][slot]=(Ka,Kb)
  __shared__ __align__(16) float GK[2][16];     // [buf][slot]=gk
  for (int idx = tid; idx < T && idx < 4096; idx += 1024)
    s_lds[idx] = s_grid[idx];
  __syncthreads();

  // ---- direction probes ----
  int delta;
  {
    float pr = (float)i;
    float pr1 = dppmov<RORc(1)>(pr);
    delta = (((int)pr1) - i) & 15;
  }
  bool p32_c_low;
  {
    float v = (float)(lane >> 5);
    float c = v, d = v;
    p32swap(c, d);
    p32_c_low = (c == 0.0f);
  }

  // ---- weight prep (identical to r7-r17) ----
  const int rA = 16 * mhi + i, hA = mlo;
  const int rB = 16 * mlo + i, hB = mhi;
  const int r_in = 16 * mlo + i;
  const int e1 = r_in;

  float w1a[16], w2a[16], m21[16];
#pragma unroll 1
  for (int k = 0; k < 16; ++k) {
    int cA = hA * 16 + ((i + delta * k) & 15);
    int cB = hB * 16 + ((i + delta * k) & 15);
    w1a[k] = W1a[rA * 32 + cA] * (-2.0f * C_TANH);
    w2a[k] = W2a[rA * 32 + cA] * (-2.0f * C_TANH);
    float acc = 0.0f;
    for (int q = 0; q < 32; ++q)
      acc = fmaf(W2a[rB * 32 + q], W1b[q * 32 + cB], acc);
    m21[k] = acc * (-2.0f * C_TANH);
  }
  float bz1a;
  {
    float rs = 0.0f;
    for (int c = 0; c < 32; ++c) rs += W1a[rA * 32 + c];
    bz1a = hA ? 0.0f : C_TANH * (b1a[rA] + rs);
  }
  float c2sel;
  {
    float rs2a = 0.0f, m21rs = 0.0f, wb = 0.0f;
    for (int q = 0; q < 32; ++q) {
      float w2q = W2a[rB * 32 + q];
      rs2a += w2q;
      float rs1bq = 0.0f;
      for (int c = 0; c < 32; ++c) rs1bq += W1b[q * 32 + c];
      m21rs = fmaf(w2q, rs1bq, m21rs);
      wb = fmaf(w2q, b1b[q], wb);
    }
    c2sel = hB ? 0.0f : C_TANH * (rs2a + m21rs + wb + b2a[rB]);
  }
  const bool seedsel = (mlo == mhi);

  float winy0 = Win[r_in * 5 + 0] * C_TANH;
  float winy1 = Win[r_in * 5 + 1] * C_TANH;
  float winy2 = Win[r_in * 5 + 2] * C_TANH;
  float winy3 = Win[r_in * 5 + 3] * C_TANH;
  float wins  = Win[r_in * 5 + 4] * C_TANH;
  float binr  = bin_[r_in] * C_TANH;
  float gsel_a = mhi ? winy2 : winy0;
  float gsel_b = mhi ? winy3 : winy1;

  const int ra_ = 2 * mhi, rb_ = 2 * mhi + 1;
  float woXa = Wout[ra_ * 32 + e1] * (-2.0f * C_NSIG);
  float woXb = Wout[rb_ * 32 + e1] * (-2.0f * C_NSIG);
  float wo1a, wo1b, wo2a, wo2b, boa, bob;
  {
    float w1s_a = 0.0f, w1s_b = 0.0f, w2s_a = 0.0f, w2s_b = 0.0f;
    float rsX_a = 0.0f, rsX_b = 0.0f, rs1_a = 0.0f, rs1_b = 0.0f;
    float rs2_a = 0.0f, rs2_b = 0.0f, bt_a = 0.0f, bt_b = 0.0f;
    for (int q = 0; q < 32; ++q) {
      float waq = Wout[ra_ * 32 + q], wbq = Wout[rb_ * 32 + q];
      w1s_a = fmaf(waq, W1b[q * 32 + e1], w1s_a);
      w1s_b = fmaf(wbq, W1b[q * 32 + e1], w1s_b);
      w2s_a = fmaf(waq, W2b[q * 32 + e1], w2s_a);
      w2s_b = fmaf(wbq, W2b[q * 32 + e1], w2s_b);
      rsX_a += waq; rsX_b += wbq;
      float rs1bq = 0.0f, rs2bq = 0.0f;
      for (int c = 0; c < 32; ++c) {
        rs1bq += W1b[q * 32 + c];
        rs2bq += W2b[q * 32 + c];
      }
      rs1_a = fmaf(waq, rs1bq, rs1_a); rs1_b = fmaf(wbq, rs1bq, rs1_b);
      rs2_a = fmaf(waq, rs2bq, rs2_a); rs2_b = fmaf(wbq, rs2bq, rs2_b);
      float bs = b1b[q] + b2b[q];
      bt_a = fmaf(waq, bs, bt_a); bt_b = fmaf(wbq, bs, bt_b);
    }
    wo1a = w1s_a * (-2.0f * C_NSIG); wo1b = w1s_b * (-2.0f * C_NSIG);
    wo2a = w2s_a * (-2.0f * C_NSIG); wo2b = w2s_b * (-2.0f * C_NSIG);
    boa = (bout[ra_] + bt_a + rsX_a + rs1_a + rs2_a) * (C_NSIG / 32.0f);
    bob = (bout[rb_] + bt_b + rsX_b + rs1_b + rs2_b) * (C_NSIG / 32.0f);
  }
  float Aa = mhi ? Aarr[2] : Aarr[0];
  float Ab = mhi ? Aarr[3] : Aarr[1];

  auto relayout = [&](float v) -> float {
    float c = v, d = v;
    p32swap(c, d);
    float lo = p32_c_low ? c : d;
    float hi = p32_c_low ? d : c;
    return mlo ? hi : lo;
  };

  float pfa, pfb, wpa, wpb, na, nb, gkv;

  auto setpref = [&](float yA, float yB) {
    float sa = frcp(1.0f + fexp2(yA * C_NSIG));
    float sb = frcp(1.0f + fexp2(yB * C_NSIG));
    pfa = 0.01f * sa * (Aa - sa);
    pfb = 0.01f * sb * (Ab - sb);
    wpa = gsel_a * pfa;
    wpb = gsel_b * pfb;
  };

  auto STAGE = [&](float zin) {
    float g0v = frcp(fexp2(zin) + 1.0f);                   // ABAB
    float u1; MV8(w1a, bz1a, g0v, u1);
    { float b = u1; p16swap(u1, b); u1 += b; }             // AABB
    float q2; MV8(w2a, 0.0f, g0v, q2);
    { float b = q2; p16swap(q2, b); q2 += b; }             // AABB
    float g1 = frcp(fexp2(u1) + 1.0f);
    float g1r = relayout(g1);
    float seed = (seedsel ? q2 : 0.0f) + c2sel;
    float u2; MV8(m21, seed, g1, u2);
    { float b = u2; p32swap(u2, b); u2 += b; }             // ABAB
    float g2 = frcp(fexp2(u2) + 1.0f);
    float ph0 = fmaf(wo1a, g1r, fmaf(woXa, g0v, boa));
    float ph1 = fmaf(wo1b, g1r, fmaf(woXb, g0v, bob));
    float p0 = fmaf(wo2a, g2, ph0);
    float p1 = fmaf(wo2b, g2, ph1);
    p0 += dppmov<RORc(8)>(p0); p1 += dppmov<RORc(8)>(p1);
    p0 += dppmov<RORc(4)>(p0); p1 += dppmov<RORc(4)>(p1);
    p0 += dppmov<RORc(2)>(p0); p1 += dppmov<RORc(2)>(p1);
    p0 += dppmov<RORc(1)>(p0); p1 += dppmov<RORc(1)>(p1);
    { float q = p0; p16swap(p0, q); p0 += q; }
    { float q = p1; p16swap(p1, q); p1 += q; }
    na = frcp(1.0f + fexp2(p0));
    nb = frcp(1.0f + fexp2(p1));
    float gp = fmaf(wpb, nb, wpa * na);
    float gq = gp;
    p32swap(gp, gq);
    gkv = gp + gq;
  };

  auto wrslot = [&](int qq, float Ka, float Kb) {
    if ((lane & 31) == 0)
      PK[qq][mhi][wv] = make_float2(Ka, Kb);
    if (lane == 0)
      GK[qq][wv] = gkv;
  };

  // ---- state (every wave tracks identically; lags the pipeline) ----
  float y00 = y0in[0], y01 = y0in[1], y02 = y0in[2], y03 = y0in[3];
  float ya = mhi ? y02 : y00;
  float yb = mhi ? y03 : y01;

  if (wv == 0 && (lane & 0x1E) == 0)
    out[(lane >> 4) + (lane & 1)] = (lane & 1) ? yb : ya;

  float zb = fmaf(winy0, y00, fmaf(winy1, y01, fmaf(winy2, y02,
             fmaf(winy3, y03, fmaf(wins, s_lds[0], binr)))));

  // ---- prologue: zero-input sweeps seed buf[1] (pseudo steps -4..-1) ----
  {
    int gi = grp < T ? grp : T - 1;
    float sg = s_lds[gi];
    setpref(ya, yb);
    STAGE(fmaf(wins, sg - s_lds[0], zb));
    wrslot(1, pfa * na, pfb * nb);
  }
  __syncthreads();

  float h6p0 = 0.0f, h6p1 = 0.0f, h6p2 = 0.0f, h6p3 = 0.0f, hsumP = 0.0f;
  const int NJ = T >> 2;   // iterations; steps 4j..4j+3 (tail evals dummy)

  for (int j = 0; j < NJ; ++j) {
    const int w = j & 1, r = w ^ 1;
    int i0 = 4 * j;
    float s0v = s_lds[i0];
    float s1v = s_lds[i0 + 1 < T ? i0 + 1 : T - 1];
    float s2v = s_lds[i0 + 2 < T ? i0 + 2 : T - 1];
    float s3v = s_lds[i0 + 3 < T ? i0 + 3 : T - 1];
    float s4v = s_lds[i0 + 4 < T ? i0 + 4 : T - 1];
    float h0 = s1v - s0v, h1 = s2v - s1v, h2 = s3v - s2v, h3 = s4v - s3v;
    float h6_0 = h0 * (1.0f / 6.0f), h6_1 = h1 * (1.0f / 6.0f);
    float h6_2 = h2 * (1.0f / 6.0f), h6_3 = h3 * (1.0f / 6.0f);

    // ---- batched reads from buf r (steps 4j-4 .. 4j-1) ----
    float4 pv0 = *(const float4*)&PK[r][mhi][0];
    float4 pv1 = *(const float4*)&PK[r][mhi][2];
    float4 pv2 = *(const float4*)&PK[r][mhi][4];
    float4 pv3 = *(const float4*)&PK[r][mhi][6];
    float4 pv4 = *(const float4*)&PK[r][mhi][8];
    float4 pv5 = *(const float4*)&PK[r][mhi][10];
    float4 pv6 = *(const float4*)&PK[r][mhi][12];
    float4 pv7 = *(const float4*)&PK[r][mhi][14];
    float4 gv0 = *(const float4*)&GK[r][0];
    float4 gv1 = *(const float4*)&GK[r][4];
    float4 gv2 = *(const float4*)&GK[r][8];
    float4 gv3 = *(const float4*)&GK[r][12];
    // RK combines {1,2,2,1} per step k=0..3
    float aC0 = fmaf(2.0f, pv0.z, pv0.x); aC0 = fmaf(2.0f, pv1.x, aC0); aC0 += pv1.z;
    float bC0 = fmaf(2.0f, pv0.w, pv0.y); bC0 = fmaf(2.0f, pv1.y, bC0); bC0 += pv1.w;
    float gC0 = fmaf(2.0f, gv0.y, gv0.x); gC0 = fmaf(2.0f, gv0.z, gC0); gC0 += gv0.w;
    float aC1 = fmaf(2.0f, pv2.z, pv2.x); aC1 = fmaf(2.0f, pv3.x, aC1); aC1 += pv3.z;
    float bC1 = fmaf(2.0f, pv2.w, pv2.y); bC1 = fmaf(2.0f, pv3.y, bC1); bC1 += pv3.w;
    float gC1 = fmaf(2.0f, gv1.y, gv1.x); gC1 = fmaf(2.0f, gv1.z, gC1); gC1 += gv1.w;
    float aC2 = fmaf(2.0f, pv4.z, pv4.x); aC2 = fmaf(2.0f, pv5.x, aC2); aC2 += pv5.z;
    float bC2 = fmaf(2.0f, pv4.w, pv4.y); bC2 = fmaf(2.0f, pv5.y, bC2); bC2 += pv5.w;
    float gC2 = fmaf(2.0f, gv2.y, gv2.x); gC2 = fmaf(2.0f, gv2.z, gC2); gC2 += gv2.w;
    float aC3 = fmaf(2.0f, pv6.z, pv6.x); aC3 = fmaf(2.0f, pv7.x, aC3); aC3 += pv7.z;
    float bC3 = fmaf(2.0f, pv6.w, pv6.y); bC3 = fmaf(2.0f, pv7.y, bC3); bC3 += pv7.w;
    float gC3 = fmaf(2.0f, gv3.y, gv3.x); gC3 = fmaf(2.0f, gv3.z, gC3); gC3 += gv3.w;
    // own-stage input history: steps 4j-2 (slots 8+sl), 4j-1 (slots 12+sl)
    const int sl = st ? st - 1 : 0;
    float2 pk0 = PK[r][mhi][8 + sl];
    float2 pk1 = PK[r][mhi][12 + sl];
    float g0i = GK[r][8 + sl], g1i = GK[r][12 + sl];

    // ---- finalize exact y(4j-3)..y(4j) (j>=1) ----
    if (j) {
      float y1a = fmaf(h6p0, aC0, ya), y1b = fmaf(h6p0, bC0, yb);
      float y2a = fmaf(h6p1, aC1, y1a), y2b = fmaf(h6p1, bC1, y1b);
      float y3a = fmaf(h6p2, aC2, y2a), y3b = fmaf(h6p2, bC2, y2b);
      ya = fmaf(h6p3, aC3, y3a);
      yb = fmaf(h6p3, bC3, y3b);
      float zacc = fmaf(h6p0, gC0, fmaf(wins, hsumP, zb));
      zacc = fmaf(h6p1, gC1, zacc);
      zacc = fmaf(h6p2, gC2, zacc);
      zb = fmaf(h6p3, gC3, zacc);
      if (wv == 0 && (lane & 0x1E) == 0) {
        const size_t t0 = (size_t)(4 * j - 3);
        const int c = (lane >> 4) + (lane & 1);
        out[t0 * 4 + c] = (lane & 1) ? y1b : y1a;
        out[(t0 + 1) * 4 + c] = (lane & 1) ? y2b : y2a;
        out[(t0 + 2) * 4 + c] = (lane & 1) ? y3b : y3a;
        out[(t0 + 3) * 4 + c] = (lane & 1) ? yb : ya;
      }
    }

    // ---- extrapolated same-step stage inputs: (g+2)*g1 - (g+1)*g0 ----
    float fg = (float)(grp + 1);
    float gin  = fmaf(fg, g1i - g0i, g1i);
    float kain = fmaf(fg, pk1.x - pk0.x, pk1.x);
    float kbin = fmaf(fg, pk1.y - pk0.y, pk1.y);

    // ---- y/zb guesses for grp>=1 via extrapolated combines ----
    float yA = ya, yB = yb;
    float sg = (grp == 0) ? s0v : (grp == 1) ? s1v : (grp == 2) ? s2v : s3v;
    float zB = fmaf(wins, sg - s0v, zb);
    float dA = aC3 - aC2, dB = bC3 - bC2, dG = gC3 - gC2;
#pragma unroll
    for (int k = 0; k < 3; ++k) {
      if (k < grp) {
        float fk = (float)(k + 1);
        float ea = fmaf(fk, dA, aC3);
        float eb = fmaf(fk, dB, bC3);
        float eg = fmaf(fk, dG, gC3);
        float h6k = (k == 0) ? h6_0 : (k == 1) ? h6_1 : h6_2;
        yA = fmaf(h6k, ea, yA);
        yB = fmaf(h6k, eb, yB);
        zB = fmaf(h6k, eg, zB);
      }
    }
    float hg = (grp == 0) ? h0 : (grp == 1) ? h1 : (grp == 2) ? h2 : h3;
    float cw = (st == 0) ? 0.0f : (st == 3) ? hg : 0.5f * hg;

    setpref(fmaf(cw, kain, yA), fmaf(cw, kbin, yB));
    STAGE(fmaf(cw, gin, zB));
    wrslot(w, pfa * na, pfb * nb);

    h6p0 = h6_0; h6p1 = h6_1; h6p2 = h6_2; h6p3 = h6_3;
    hsumP = (h0 + h1) + (h2 + h3);
    __syncthreads();
  }

  // ---- epilogue: finalize y(T-3)..y(T-1) from last-written buf ----
  if (T > 1) {
    const int rr = (NJ - 1) & 1;
    float4 pv0 = *(const float4*)&PK[rr][mhi][0];
    float4 pv1 = *(const float4*)&PK[rr][mhi][2];
    float4 pv2 = *(const float4*)&PK[rr][mhi][4];
    float4 pv3 = *(const float4*)&PK[rr][mhi][6];
    float4 pv4 = *(const float4*)&PK[rr][mhi][8];
    float4 pv5 = *(const float4*)&PK[rr][mhi][10];
    float aC0 = fmaf(2.0f, pv0.z, pv0.x); aC0 = fmaf(2.0f, pv1.x, aC0); aC0 += pv1.z;
    float bC0 = fmaf(2.0f, pv0.w, pv0.y); bC0 = fmaf(2.0f, pv1.y, bC0); bC0 += pv1.w;
    float aC1 = fmaf(2.0f, pv2.z, pv2.x); aC1 = fmaf(2.0f, pv3.x, aC1); aC1 += pv3.z;
    float bC1 = fmaf(2.0f, pv2.w, pv2.y); bC1 = fmaf(2.0f, pv3.y, bC1); bC1 += pv3.w;
    float aC2 = fmaf(2.0f, pv4.z, pv4.x); aC2 = fmaf(2.0f, pv5.x, aC2); aC2 += pv5.z;
    float bC2 = fmaf(2.0f, pv4.w, pv4.y); bC2 = fmaf(2.0f, pv5.y, bC2); bC2 += pv5.w;
    float y1a = fmaf(h6p0, aC0, ya), y1b = fmaf(h6p0, bC0, yb);
    float y2a = fmaf(h6p1, aC1, y1a), y2b = fmaf(h6p1, bC1, y1b);
    float y3a = fmaf(h6p2, aC2, y2a), y3b = fmaf(h6p2, bC2, y2b);
    if (wv == 0 && (lane & 0x1E) == 0) {
      const size_t t0 = (size_t)(T - 3);
      const int c = (lane >> 4) + (lane & 1);
      out[t0 * 4 + c] = (lane & 1) ? y1b : y1a;
      out[(t0 + 1) * 4 + c] = (lane & 1) ? y2b : y2a;
      out[(t0 + 2) * 4 + c] = (lane & 1) ? y3b : y3a;
    }
  }
}

extern "C" void kernel_launch(void* const* d_in, const int* in_sizes, int n_in,
                              void* d_out, int out_size, void* d_ws, size_t ws_size,
                              hipStream_t stream) {
  const float* s_grid = (const float*)d_in[0];
  const float* y0 = (const float*)d_in[1];
  const float* Win = (const float*)d_in[2];
  const float* bin_ = (const float*)d_in[3];
  const float* W1a = (const float*)d_in[4];
  const float* b1a = (const float*)d_in[5];
  const float* W1b = (const float*)d_in[6];
  const float* b1b = (const float*)d_in[7];
  const float* W2a = (const float*)d_in[8];
  const float* b2a = (const float*)d_in[9];
  const float* W2b = (const float*)d_in[10];
  const float* b2b = (const float*)d_in[11];
  const float* Wout = (const float*)d_in[12];
  const float* bout = (const float*)d_in[13];
  const float* A = (const float*)d_in[14];
  int T = in_sizes[0];

  ode_kernel<<<1, 1024, 0, stream>>>(s_grid, y0, Win, bin_, W1a, b1a, W1b, b1b,
                                     W2a, b2a, W2b, b2b, Wout, bout, A,
                                     (float*)d_out, T);
}